// Round 4
// baseline (369.638 us; speedup 1.0000x reference)
//
#include <hip/hip_runtime.h>
#include <stdint.h>

typedef unsigned short u16;
typedef short bf16x8 __attribute__((ext_vector_type(8)));
typedef float f32x4 __attribute__((ext_vector_type(4)));
typedef float f32x16 __attribute__((ext_vector_type(16)));
typedef uint32_t u32x4 __attribute__((ext_vector_type(4)));

#define NB   128
#define SEQ  512
#define EMB  192
#define NTOK (NB * SEQ)   // 65536
#define F1DIM 384
#define ATTW 192          // att buffer row (u16): cols 0..95 attn heads, 96..191 conv(x1)
#define VTP  520          // V^T row stride (u16)
#define KTS  24           // K row stride (u16)
#define XnS  200          // xn/tn/x1b LDS row stride (u16): 400B, 16B-aligned
#define H1S  392          // h1 LDS row stride (u16): 784B, 16B-aligned

__device__ __forceinline__ float bf2f(u16 u) {
  union { uint32_t u; float f; } v; v.u = ((uint32_t)u) << 16; return v.f;
}
__device__ __forceinline__ u16 f2bf(float f) {
  union { float f; uint32_t u; } v; v.f = f;
  uint32_t r = v.u + 0x7fffu + ((v.u >> 16) & 1u);
  return (u16)(r >> 16);
}
__device__ __forceinline__ uint32_t pack2bf(float a, float b) {
  return (uint32_t)f2bf(a) | ((uint32_t)f2bf(b) << 16);
}

// ---------------- pack all weights (one launch) ----------------------------
__global__ __launch_bounds__(256) void pack_kernel(const float* __restrict__ w1,
    const float* __restrict__ w2, const float* __restrict__ wqa,
    const float* __restrict__ wqg, const float* __restrict__ woa,
    const float* __restrict__ wog, u16* __restrict__ w1b, u16* __restrict__ w2b,
    u16* __restrict__ wqp, u16* __restrict__ wop) {
  int idx = (int)blockIdx.x * 256 + (int)threadIdx.x;
  if (idx < 73728) {
    w1b[idx] = f2bf(w1[idx]);
  } else if (idx < 147456) {
    w2b[idx - 73728] = f2bf(w2[idx - 73728]);
  } else if (idx < 165888) {
    int i = idx - 147456;
    int row = i >> 6, k = i & 63;
    float v = 0.0f;
    if (k < 48) v = (row < 144) ? wqa[row * 48 + k] : wqg[(row - 144) * 48 + k];
    wqp[i] = f2bf(v);
  } else if (idx < 172032) {
    int i = idx - 165888;
    int row = i >> 6, k = i & 63;
    float v = 0.0f;
    if (k < 48) v = (row < 48) ? woa[row * 48 + k] : wog[(row - 48) * 48 + k];
    wop[i] = f2bf(v);
  }
}

// ---------------- fused LN1 + QKV-proj (MFMA) + conv -----------------------
// conv result (+x residual) goes as bf16 into att cols 96..191 (no fp32 out).
__global__ __launch_bounds__(256) void ln1_qkv_conv_kernel(
    const float* __restrict__ x, const float* __restrict__ g,
    const float* __restrict__ b, const u16* __restrict__ wq,
    const float* __restrict__ bacc, const float* __restrict__ bgyr,
    const float* __restrict__ cw, u16* __restrict__ qkv,
    u16* __restrict__ att) {
  __shared__ u16 Xn[64 * XnS];
  int bm = (int)blockIdx.x * 64;
  int tid = threadIdx.x;
  int trow = tid >> 2, part = tid & 3;
  int tok = bm + trow;
  const float* xr = x + (size_t)tok * EMB + part * 48;
  float vals[48];
#pragma unroll
  for (int j = 0; j < 48; j += 4) {
    float4 v = *(const float4*)(xr + j);
    vals[j] = v.x; vals[j + 1] = v.y; vals[j + 2] = v.z; vals[j + 3] = v.w;
  }
  float s = 0.0f, s2 = 0.0f;
#pragma unroll
  for (int j = 0; j < 48; j++) { s += vals[j]; s2 += vals[j] * vals[j]; }
  s += __shfl_xor(s, 1); s2 += __shfl_xor(s2, 1);
  s += __shfl_xor(s, 2); s2 += __shfl_xor(s2, 2);
  float mean = s * (1.0f / EMB);
  float var  = s2 * (1.0f / EMB) - mean * mean;
  float rs   = rsqrtf(var + 1e-6f);
  {
    u16* xnrow = Xn + trow * XnS + part * 48;
    const float* gp = g + part * 48;
    const float* bp = b + part * 48;
#pragma unroll
    for (int j = 0; j < 48; j += 2) {
      uint32_t w = pack2bf((vals[j] - mean) * rs * gp[j] + bp[j],
                           (vals[j + 1] - mean) * rs * gp[j + 1] + bp[j + 1]);
      *(uint32_t*)(xnrow + j) = w;
    }
  }
  __syncthreads();
  int wid = tid >> 6, lane = tid & 63;
  int l15 = lane & 15, quad = lane >> 4;
  const u16* arow_l = Xn + (wid * 16 + l15) * XnS;
  f32x4 acc[18] = {};
#pragma unroll
  for (int ks = 0; ks < 2; ks++) {
    int kk = ks * 32;
    bf16x8 af_a = *(const bf16x8*)(arow_l + kk + quad * 8);
    bf16x8 af_g = *(const bf16x8*)(arow_l + 96 + kk + quad * 8);
#pragma unroll
    for (int st = 0; st < 18; st++) {
      bf16x8 bf = *(const bf16x8*)(wq + (size_t)(st * 16 + l15) * 64 + kk + quad * 8);
      acc[st] = __builtin_amdgcn_mfma_f32_16x16x32_bf16(st < 9 ? af_a : af_g,
                                                        bf, acc[st], 0, 0, 0);
    }
  }
#pragma unroll
  for (int st = 0; st < 18; st++) {
    int col = st * 16 + l15;
    int cc = (col < 144) ? col : col - 144;
    float bias = (col < 144) ? bacc[cc] : bgyr[cc];
    float qs = (cc < 48) ? 0.36067376022f : 1.0f;  // 0.25*log2(e): exp2-domain scores
#pragma unroll
    for (int r = 0; r < 4; r++) {
      int orow = bm + wid * 16 + quad * 4 + r;
      qkv[(size_t)orow * 288 + col] = f2bf((acc[st][r] + bias) * qs);
    }
  }
  {
    int wr = trow & 3;
    float w15[15];
#pragma unroll
    for (int k = 0; k < 15; k++) w15[k] = cw[wr * 15 + k];
    float win[38];
    int base = part * 24 - 7;
#pragma unroll
    for (int i = 0; i < 38; i++) {
      int p = base + i;
      win[i] = (p >= 0 && p < 96) ? bf2f(Xn[trow * XnS + 48 + p]) : 0.0f;
    }
    const float* xres = x + (size_t)tok * EMB + 48 + part * 24;
    u16* orow = att + (size_t)tok * ATTW + 96 + part * 24;
#pragma unroll
    for (int c = 0; c < 24; c += 4) {
      float4 r4 = *(const float4*)(xres + c);
      float o[4];
#pragma unroll
      for (int u = 0; u < 4; u++) {
        float sc = 0.0f;
#pragma unroll
        for (int k = 0; k < 15; k++) sc += win[c + u + k] * w15[k];
        o[u] = sc;
      }
      *(uint32_t*)(orow + c)     = pack2bf(o[0] + r4.x, o[1] + r4.y);
      *(uint32_t*)(orow + c + 2) = pack2bf(o[2] + r4.z, o[3] + r4.w);
    }
  }
}

// ---------------- MFMA flash attention, max-free exp2 softmax --------------
__global__ __launch_bounds__(256) void attn_kernel(const u16* __restrict__ qkv,
                                                   u16* __restrict__ att) {
  __shared__ u16 Kt[SEQ * KTS];
  __shared__ u16 Vt[17 * VTP];
  int bid = blockIdx.x;
  int hh  = bid % 3;
  int brb = (bid / 3) & 1;
  int b   = bid / 6;
  int tid = threadIdx.x;
  size_t tokbase = (size_t)b * SEQ;
  int qoff = brb * 144 + hh * 16;
  int koff = qoff + 48;
  int voff = qoff + 96;
  for (int r = tid; r < SEQ; r += 256) {
    const u16* src = qkv + (tokbase + r) * 288;
    *(uint4*)(Kt + r * KTS)     = *(const uint4*)(src + koff);
    *(uint4*)(Kt + r * KTS + 8) = *(const uint4*)(src + koff + 8);
    u16 tmp[16];
    *(uint4*)(tmp)     = *(const uint4*)(src + voff);
    *(uint4*)(tmp + 8) = *(const uint4*)(src + voff + 8);
#pragma unroll
    for (int j = 0; j < 16; j++) Vt[j * VTP + r] = tmp[j];
  }
  Vt[16 * VTP + tid]       = 0x3F80;  // ones row -> l from the PV MFMA
  Vt[16 * VTP + 256 + tid] = 0x3F80;
  __syncthreads();
  int wave = tid >> 6, lane = tid & 63;
  int q31 = lane & 31, h = lane >> 5;
  int dcl = (q31 < 16) ? q31 : 16;
#pragma unroll 1
  for (int qi = 0; qi < 4; qi++) {
    int qrow = (wave * 4 + qi) * 32 + q31;
    bf16x8 qfrag = *(const bf16x8*)(qkv + (tokbase + qrow) * 288 + qoff + h * 8);
    f32x16 Ot = {};
#pragma unroll 2
    for (int kt = 0; kt < 16; kt++) {
      bf16x8 kfrag = *(const bf16x8*)(Kt + (kt * 32 + q31) * KTS + h * 8);
      f32x16 zc = {};
      f32x16 S = __builtin_amdgcn_mfma_f32_32x32x16_bf16(kfrag, qfrag, zc, 0, 0, 0);
      uint32_t pk[8], swk[8];
#pragma unroll
      for (int i = 0; i < 8; i++) {
        union { float f; uint32_t u; } a0, a1;
        a0.f = exp2f(S[2 * i]);
        a1.f = exp2f(S[2 * i + 1]);
        pk[i] = __builtin_amdgcn_perm(a1.u, a0.u, 0x07060302u);
        swk[i] = (uint32_t)__shfl_xor((int)pk[i], 32);
      }
      u32x4 t1 = { h ? swk[2] : pk[0], h ? swk[3] : pk[1],
                   h ? pk[2]  : swk[0], h ? pk[3]  : swk[1] };
      u32x4 t2 = { h ? swk[6] : pk[4], h ? swk[7] : pk[5],
                   h ? pk[6]  : swk[4], h ? pk[7]  : swk[5] };
      bf16x8 pb1 = __builtin_bit_cast(bf16x8, t1);
      bf16x8 pb2 = __builtin_bit_cast(bf16x8, t2);
      bf16x8 av1 = *(const bf16x8*)(Vt + dcl * VTP + kt * 32 + h * 8);
      bf16x8 av2 = *(const bf16x8*)(Vt + dcl * VTP + kt * 32 + 16 + h * 8);
      Ot = __builtin_amdgcn_mfma_f32_32x32x16_bf16(av1, pb1, Ot, 0, 0, 0);
      Ot = __builtin_amdgcn_mfma_f32_32x32x16_bf16(av2, pb2, Ot, 0, 0, 0);
    }
    float inv = 1.0f / Ot[8];
    u16* orow = att + (tokbase + qrow) * ATTW + brb * 48 + hh * 16 + 4 * h;
    uint2 st0 = { pack2bf(Ot[0] * inv, Ot[1] * inv),
                  pack2bf(Ot[2] * inv, Ot[3] * inv) };
    uint2 st1 = { pack2bf(Ot[4] * inv, Ot[5] * inv),
                  pack2bf(Ot[6] * inv, Ot[7] * inv) };
    *(uint2*)(orow)     = st0;
    *(uint2*)(orow + 8) = st1;
  }
}

// ---------------- fused tail: out-proj + residual + LN2 + FFN --------------
// 512 threads, 32 tokens/block. Same LDS as round-1 (37,888B, Tn/H1 alias)
// -> 4 blocks/CU, but 8 waves/block -> 32-wave residency cap (2x round 1's
// 16). Per-wave phase work halved: gemm1 acc1[6] (1 m-tile), gemm2 acc2[3].
// Weight traffic identical to the 98us round-1 config (2048 blocks); the
// extra waves exist purely to hide the L2 weight-load latency that bounded
// it. No launch-bounds min-waves (round-2 spill lesson).
__global__ __launch_bounds__(512) void tail_kernel(
    const u16* __restrict__ att, const u16* __restrict__ wo,
    const float* __restrict__ boacc, const float* __restrict__ bogyr,
    const float* __restrict__ x, const float* __restrict__ g2,
    const float* __restrict__ b2v, const u16* __restrict__ w1b,
    const float* __restrict__ b1, const u16* __restrict__ w2b,
    const float* __restrict__ b2, float* __restrict__ out) {
  __shared__ u16 LDSB[32 * XnS + 32 * H1S];  // 12800B X1b + 25088B region R
  u16* X1b = LDSB;
  u16* Tn  = LDSB + 32 * XnS;
  u16* H1  = LDSB + 32 * XnS;  // aliases Tn (Tn dead before H1 write)
  int bm = (int)blockIdx.x * 32;
  int tid = threadIdx.x;
  int wid = tid >> 6, lane = tid & 63;
  int l15 = lane & 15, quad = lane >> 4;

  // phase 0/1: waves 6-7 copy conv cols; waves 0-5 out-proj (1 col-tile each,
  // 2 m-tiles)
  if (wid >= 6) {
    int trow = (wid - 6) * 16 + (lane >> 2), p4 = lane & 3;  // 24 u16 each
    const u16* src = att + (size_t)(bm + trow) * ATTW + 96 + p4 * 24;
    u16* dst = X1b + trow * XnS + 48 + p4 * 24;
    *(uint4*)(dst)      = *(const uint4*)(src);
    *(uint4*)(dst + 8)  = *(const uint4*)(src + 8);
    *(uint4*)(dst + 16) = *(const uint4*)(src + 16);
  } else {
    int st = wid;
    int ng = (st >= 3) ? 1 : 0;
    f32x4 acc[2] = {};
    bf16x8 wf[2];
#pragma unroll
    for (int ks = 0; ks < 2; ks++)
      wf[ks] = *(const bf16x8*)(wo + (size_t)(st * 16 + l15) * 64 + ks * 32 + quad * 8);
#pragma unroll
    for (int m = 0; m < 2; m++) {
      const u16* arow = att + (size_t)(bm + m * 16 + l15) * ATTW + (ng ? 48 : 0);
#pragma unroll
      for (int ks = 0; ks < 2; ks++) {
        bf16x8 af = *(const bf16x8*)(arow + ks * 32 + quad * 8);
        acc[m] = __builtin_amdgcn_mfma_f32_16x16x32_bf16(af, wf[ks], acc[m], 0, 0, 0);
      }
    }
    int col = st * 16 + l15;
    float bias = (col < 48) ? boacc[col] : bogyr[col - 48];
    int oc = (col < 48) ? col : col + 96;
#pragma unroll
    for (int m = 0; m < 2; m++) {
#pragma unroll
      for (int r = 0; r < 4; r++) {
        int lrow = m * 16 + quad * 4 + r;
        float v = acc[m][r] + bias + x[(size_t)(bm + lrow) * EMB + oc];
        X1b[lrow * XnS + oc] = f2bf(v);
      }
    }
  }
  __syncthreads();

  // phase 2: LN2 from X1b -> Tn (16 threads/token, 12 cols each; 512 thr = 32 tok)
  {
    int trow = tid >> 4, part = tid & 15;
    const u16* xl = X1b + trow * XnS + part * 12;
    u16 raw[12];
    *(uint2*)(raw)     = *(const uint2*)(xl);
    *(uint2*)(raw + 4) = *(const uint2*)(xl + 4);
    *(uint2*)(raw + 8) = *(const uint2*)(xl + 8);
    float vals[12];
#pragma unroll
    for (int j = 0; j < 12; j++) vals[j] = bf2f(raw[j]);
    float s = 0.0f, s2 = 0.0f;
#pragma unroll
    for (int j = 0; j < 12; j++) { s += vals[j]; s2 += vals[j] * vals[j]; }
    s += __shfl_xor(s, 1); s2 += __shfl_xor(s2, 1);
    s += __shfl_xor(s, 2); s2 += __shfl_xor(s2, 2);
    s += __shfl_xor(s, 4); s2 += __shfl_xor(s2, 4);
    s += __shfl_xor(s, 8); s2 += __shfl_xor(s2, 8);
    float mean = s * (1.0f / EMB);
    float var  = s2 * (1.0f / EMB) - mean * mean;
    float rs   = rsqrtf(var + 1e-6f);
    u16* trp = Tn + trow * XnS + part * 12;
    const float* gp = g2 + part * 12;
    const float* bp = b2v + part * 12;
#pragma unroll
    for (int j = 0; j < 12; j += 2) {
      uint32_t w = pack2bf((vals[j] - mean) * rs * gp[j] + bp[j],
                           (vals[j + 1] - mean) * rs * gp[j + 1] + bp[j + 1]);
      *(uint32_t*)(trp + j) = w;
    }
  }
  __syncthreads();

  // phase 3: gemm1 fully in registers (Tn readable until the barrier below)
  // wave (mg, ng): m-tile mg, 96 cols (6 stl)
  int mg = wid & 1, ng = wid >> 1;
  f32x4 acc1[6] = {};
#pragma unroll
  for (int kk = 0; kk < 192; kk += 32) {
    bf16x8 a0 = *(const bf16x8*)(Tn + (mg * 16 + l15) * XnS + kk + quad * 8);
#pragma unroll
    for (int stl = 0; stl < 6; stl++) {
      bf16x8 bf = *(const bf16x8*)(w1b + (size_t)((ng * 6 + stl) * 16 + l15) * EMB + kk + quad * 8);
      acc1[stl] = __builtin_amdgcn_mfma_f32_16x16x32_bf16(a0, bf, acc1[stl], 0, 0, 0);
    }
  }
  __syncthreads();  // all Tn reads complete -> safe to overwrite with H1
#pragma unroll
  for (int stl = 0; stl < 6; stl++) {
    int col = (ng * 6 + stl) * 16 + l15;
    float bias = b1[col];
#pragma unroll
    for (int r = 0; r < 4; r++) {
      float v = acc1[stl][r] + bias;
      v = v > 0.0f ? v : 0.0f;
      H1[(mg * 16 + quad * 4 + r) * H1S + col] = f2bf(v);
    }
  }
  __syncthreads();

  // phase 4: gemm2 + final write: out = bf2f(X1b) + relu(h1@w2^T + b2)
  // wave (mg, ng): m-tile mg, 48 cols (3 stl)
  {
    f32x4 acc2[3] = {};
#pragma unroll
    for (int kk = 0; kk < 384; kk += 32) {
      bf16x8 a0 = *(const bf16x8*)(H1 + (mg * 16 + l15) * H1S + kk + quad * 8);
#pragma unroll
      for (int stl = 0; stl < 3; stl++) {
        bf16x8 bf = *(const bf16x8*)(w2b + (size_t)((ng * 3 + stl) * 16 + l15) * F1DIM + kk + quad * 8);
        acc2[stl] = __builtin_amdgcn_mfma_f32_16x16x32_bf16(a0, bf, acc2[stl], 0, 0, 0);
      }
    }
#pragma unroll
    for (int stl = 0; stl < 3; stl++) {
      int col = (ng * 3 + stl) * 16 + l15;
      float bias = b2[col];
#pragma unroll
      for (int r = 0; r < 4; r++) {
        int lrow = mg * 16 + quad * 4 + r;
        float v = acc2[stl][r] + bias;
        v = v > 0.0f ? v : 0.0f;
        out[(size_t)(bm + lrow) * EMB + col] = v + bf2f(X1b[lrow * XnS + col]);
      }
    }
  }
}

extern "C" void kernel_launch(void* const* d_in, const int* in_sizes, int n_in,
                              void* d_out, int out_size, void* d_ws, size_t ws_size,
                              hipStream_t stream) {
  const float* x         = (const float*)d_in[0];
  const float* ln1_g     = (const float*)d_in[1];
  const float* ln1_b     = (const float*)d_in[2];
  const float* acc_wqkv  = (const float*)d_in[3];
  const float* acc_bqkv  = (const float*)d_in[4];
  const float* acc_wo    = (const float*)d_in[5];
  const float* acc_bo    = (const float*)d_in[6];
  const float* gyro_wqkv = (const float*)d_in[7];
  const float* gyro_bqkv = (const float*)d_in[8];
  const float* gyro_wo   = (const float*)d_in[9];
  const float* gyro_bo   = (const float*)d_in[10];
  const float* conv_w    = (const float*)d_in[11];
  const float* ln2_g     = (const float*)d_in[12];
  const float* ln2_b     = (const float*)d_in[13];
  const float* w1        = (const float*)d_in[14];
  const float* b1        = (const float*)d_in[15];
  const float* w2        = (const float*)d_in[16];
  const float* b2        = (const float*)d_in[17];
  float* out = (float*)d_out;
  char* ws = (char*)d_ws;

  u16* qkvb = (u16*)(ws);                      // [N,288] bf16  37,748,736
  u16* attb = (u16*)(ws + 37748736);           // [N,192] bf16  25,165,824
  u16* w1b  = (u16*)(ws + 62914560);           // 147,456
  u16* w2b  = (u16*)(ws + 63062016);           // 147,456
  u16* wqp  = (u16*)(ws + 63209472);           // 36,864
  u16* wop  = (u16*)(ws + 63246336);           // 12,288

  pack_kernel<<<672, 256, 0, stream>>>(w1, w2, acc_wqkv, gyro_wqkv, acc_wo,
                                       gyro_wo, w1b, w2b, wqp, wop);
  ln1_qkv_conv_kernel<<<NTOK / 64, 256, 0, stream>>>(
      x, ln1_g, ln1_b, wqp, acc_bqkv, gyro_bqkv, conv_w, qkvb, attb);
  attn_kernel<<<NB * 6, 256, 0, stream>>>(qkvb, attb);
  tail_kernel<<<NTOK / 32, 512, 0, stream>>>(
      attb, wop, acc_bo, gyro_bo, x, ln2_g, ln2_b, w1b, b1, w2b, b2, out);
}

// Round 6
// 336.904 us; speedup vs baseline: 1.0972x; 1.0972x over previous
//
#include <hip/hip_runtime.h>
#include <stdint.h>

typedef unsigned short u16;
typedef short bf16x8 __attribute__((ext_vector_type(8)));
typedef float f32x4 __attribute__((ext_vector_type(4)));
typedef float f32x16 __attribute__((ext_vector_type(16)));
typedef uint32_t u32x4 __attribute__((ext_vector_type(4)));

#define NB   128
#define SEQ  512
#define EMB  192
#define NTOK (NB * SEQ)   // 65536
#define F1DIM 384
#define ATTW 192          // att row (u16): x1 cols 0..47 & 144..191 at slots 0..95 after outproj; conv(x1[48:144]) at 96..191
#define VTP  520          // V^T row stride (u16)
#define KTS  24           // K row stride (u16)
#define XnS  200          // xn/x1 LDS row stride (u16): 400B, 16B-aligned
#define TNW  192          // tn global row (u16)
#define H1W  384          // h1 global row (u16)
#define W1S  200          // w1 LDS row stride (u16): 400B, 2-way bank alias only
#define W2S  392          // w2 LDS row stride (u16): 784B, 2-way bank alias only

__device__ __forceinline__ float bf2f(u16 u) {
  union { uint32_t u; float f; } v; v.u = ((uint32_t)u) << 16; return v.f;
}
__device__ __forceinline__ u16 f2bf(float f) {
  union { float f; uint32_t u; } v; v.f = f;
  uint32_t r = v.u + 0x7fffu + ((v.u >> 16) & 1u);
  return (u16)(r >> 16);
}
__device__ __forceinline__ uint32_t pack2bf(float a, float b) {
  return (uint32_t)f2bf(a) | ((uint32_t)f2bf(b) << 16);
}

// ---------------- pack all weights (one launch) ----------------------------
__global__ __launch_bounds__(256) void pack_kernel(const float* __restrict__ w1,
    const float* __restrict__ w2, const float* __restrict__ wqa,
    const float* __restrict__ wqg, const float* __restrict__ woa,
    const float* __restrict__ wog, u16* __restrict__ w1b, u16* __restrict__ w2b,
    u16* __restrict__ wqp, u16* __restrict__ wop) {
  int idx = (int)blockIdx.x * 256 + (int)threadIdx.x;
  if (idx < 73728) {
    w1b[idx] = f2bf(w1[idx]);
  } else if (idx < 147456) {
    w2b[idx - 73728] = f2bf(w2[idx - 73728]);
  } else if (idx < 165888) {
    int i = idx - 147456;
    int row = i >> 6, k = i & 63;
    float v = 0.0f;
    if (k < 48) v = (row < 144) ? wqa[row * 48 + k] : wqg[(row - 144) * 48 + k];
    wqp[i] = f2bf(v);
  } else if (idx < 172032) {
    int i = idx - 165888;
    int row = i >> 6, k = i & 63;
    float v = 0.0f;
    if (k < 48) v = (row < 48) ? woa[row * 48 + k] : wog[(row - 48) * 48 + k];
    wop[i] = f2bf(v);
  }
}

// ---------------- fused LN1 + QKV-proj (MFMA) + conv -----------------------
__global__ __launch_bounds__(256) void ln1_qkv_conv_kernel(
    const float* __restrict__ x, const float* __restrict__ g,
    const float* __restrict__ b, const u16* __restrict__ wq,
    const float* __restrict__ bacc, const float* __restrict__ bgyr,
    const float* __restrict__ cw, u16* __restrict__ qkv,
    u16* __restrict__ att) {
  __shared__ u16 Xn[64 * XnS];
  int bm = (int)blockIdx.x * 64;
  int tid = threadIdx.x;
  int trow = tid >> 2, part = tid & 3;
  int tok = bm + trow;
  const float* xr = x + (size_t)tok * EMB + part * 48;
  float vals[48];
#pragma unroll
  for (int j = 0; j < 48; j += 4) {
    float4 v = *(const float4*)(xr + j);
    vals[j] = v.x; vals[j + 1] = v.y; vals[j + 2] = v.z; vals[j + 3] = v.w;
  }
  float s = 0.0f, s2 = 0.0f;
#pragma unroll
  for (int j = 0; j < 48; j++) { s += vals[j]; s2 += vals[j] * vals[j]; }
  s += __shfl_xor(s, 1); s2 += __shfl_xor(s2, 1);
  s += __shfl_xor(s, 2); s2 += __shfl_xor(s2, 2);
  float mean = s * (1.0f / EMB);
  float var  = s2 * (1.0f / EMB) - mean * mean;
  float rs   = rsqrtf(var + 1e-6f);
  {
    u16* xnrow = Xn + trow * XnS + part * 48;
    const float* gp = g + part * 48;
    const float* bp = b + part * 48;
#pragma unroll
    for (int j = 0; j < 48; j += 2) {
      uint32_t w = pack2bf((vals[j] - mean) * rs * gp[j] + bp[j],
                           (vals[j + 1] - mean) * rs * gp[j + 1] + bp[j + 1]);
      *(uint32_t*)(xnrow + j) = w;
    }
  }
  __syncthreads();
  int wid = tid >> 6, lane = tid & 63;
  int l15 = lane & 15, quad = lane >> 4;
  const u16* arow_l = Xn + (wid * 16 + l15) * XnS;
  f32x4 acc[18] = {};
#pragma unroll
  for (int ks = 0; ks < 2; ks++) {
    int kk = ks * 32;
    bf16x8 af_a = *(const bf16x8*)(arow_l + kk + quad * 8);
    bf16x8 af_g = *(const bf16x8*)(arow_l + 96 + kk + quad * 8);
#pragma unroll
    for (int st = 0; st < 18; st++) {
      bf16x8 bf = *(const bf16x8*)(wq + (size_t)(st * 16 + l15) * 64 + kk + quad * 8);
      acc[st] = __builtin_amdgcn_mfma_f32_16x16x32_bf16(st < 9 ? af_a : af_g,
                                                        bf, acc[st], 0, 0, 0);
    }
  }
#pragma unroll
  for (int st = 0; st < 18; st++) {
    int col = st * 16 + l15;
    int cc = (col < 144) ? col : col - 144;
    float bias = (col < 144) ? bacc[cc] : bgyr[cc];
    float qs = (cc < 48) ? 0.36067376022f : 1.0f;  // 0.25*log2(e): exp2-domain scores
#pragma unroll
    for (int r = 0; r < 4; r++) {
      int orow = bm + wid * 16 + quad * 4 + r;
      qkv[(size_t)orow * 288 + col] = f2bf((acc[st][r] + bias) * qs);
    }
  }
  {
    int wr = trow & 3;
    float w15[15];
#pragma unroll
    for (int k = 0; k < 15; k++) w15[k] = cw[wr * 15 + k];
    float win[38];
    int base = part * 24 - 7;
#pragma unroll
    for (int i = 0; i < 38; i++) {
      int p = base + i;
      win[i] = (p >= 0 && p < 96) ? bf2f(Xn[trow * XnS + 48 + p]) : 0.0f;
    }
    const float* xres = x + (size_t)tok * EMB + 48 + part * 24;
    u16* orow = att + (size_t)tok * ATTW + 96 + part * 24;
#pragma unroll
    for (int c = 0; c < 24; c += 4) {
      float4 r4 = *(const float4*)(xres + c);
      float o[4];
#pragma unroll
      for (int u = 0; u < 4; u++) {
        float sc = 0.0f;
#pragma unroll
        for (int k = 0; k < 15; k++) sc += win[c + u + k] * w15[k];
        o[u] = sc;
      }
      *(uint32_t*)(orow + c)     = pack2bf(o[0] + r4.x, o[1] + r4.y);
      *(uint32_t*)(orow + c + 2) = pack2bf(o[2] + r4.z, o[3] + r4.w);
    }
  }
}

// ---------------- MFMA flash attention, max-free exp2 softmax --------------
__global__ __launch_bounds__(256) void attn_kernel(const u16* __restrict__ qkv,
                                                   u16* __restrict__ att) {
  __shared__ u16 Kt[SEQ * KTS];
  __shared__ u16 Vt[17 * VTP];
  int bid = blockIdx.x;
  int hh  = bid % 3;
  int brb = (bid / 3) & 1;
  int b   = bid / 6;
  int tid = threadIdx.x;
  size_t tokbase = (size_t)b * SEQ;
  int qoff = brb * 144 + hh * 16;
  int koff = qoff + 48;
  int voff = qoff + 96;
  for (int r = tid; r < SEQ; r += 256) {
    const u16* src = qkv + (tokbase + r) * 288;
    *(uint4*)(Kt + r * KTS)     = *(const uint4*)(src + koff);
    *(uint4*)(Kt + r * KTS + 8) = *(const uint4*)(src + koff + 8);
    u16 tmp[16];
    *(uint4*)(tmp)     = *(const uint4*)(src + voff);
    *(uint4*)(tmp + 8) = *(const uint4*)(src + voff + 8);
#pragma unroll
    for (int j = 0; j < 16; j++) Vt[j * VTP + r] = tmp[j];
  }
  Vt[16 * VTP + tid]       = 0x3F80;  // ones row -> l from the PV MFMA
  Vt[16 * VTP + 256 + tid] = 0x3F80;
  __syncthreads();
  int wave = tid >> 6, lane = tid & 63;
  int q31 = lane & 31, h = lane >> 5;
  int dcl = (q31 < 16) ? q31 : 16;
#pragma unroll 1
  for (int qi = 0; qi < 4; qi++) {
    int qrow = (wave * 4 + qi) * 32 + q31;
    bf16x8 qfrag = *(const bf16x8*)(qkv + (tokbase + qrow) * 288 + qoff + h * 8);
    f32x16 Ot = {};
#pragma unroll 2
    for (int kt = 0; kt < 16; kt++) {
      bf16x8 kfrag = *(const bf16x8*)(Kt + (kt * 32 + q31) * KTS + h * 8);
      f32x16 zc = {};
      f32x16 S = __builtin_amdgcn_mfma_f32_32x32x16_bf16(kfrag, qfrag, zc, 0, 0, 0);
      uint32_t pk[8], swk[8];
#pragma unroll
      for (int i = 0; i < 8; i++) {
        union { float f; uint32_t u; } a0, a1;
        a0.f = exp2f(S[2 * i]);
        a1.f = exp2f(S[2 * i + 1]);
        pk[i] = __builtin_amdgcn_perm(a1.u, a0.u, 0x07060302u);
        swk[i] = (uint32_t)__shfl_xor((int)pk[i], 32);
      }
      u32x4 t1 = { h ? swk[2] : pk[0], h ? swk[3] : pk[1],
                   h ? pk[2]  : swk[0], h ? pk[3]  : swk[1] };
      u32x4 t2 = { h ? swk[6] : pk[4], h ? swk[7] : pk[5],
                   h ? pk[6]  : swk[4], h ? pk[7]  : swk[5] };
      bf16x8 pb1 = __builtin_bit_cast(bf16x8, t1);
      bf16x8 pb2 = __builtin_bit_cast(bf16x8, t2);
      bf16x8 av1 = *(const bf16x8*)(Vt + dcl * VTP + kt * 32 + h * 8);
      bf16x8 av2 = *(const bf16x8*)(Vt + dcl * VTP + kt * 32 + 16 + h * 8);
      Ot = __builtin_amdgcn_mfma_f32_32x32x16_bf16(av1, pb1, Ot, 0, 0, 0);
      Ot = __builtin_amdgcn_mfma_f32_32x32x16_bf16(av2, pb2, Ot, 0, 0, 0);
    }
    float inv = 1.0f / Ot[8];
    u16* orow = att + (tokbase + qrow) * ATTW + brb * 48 + hh * 16 + 4 * h;
    uint2 st0 = { pack2bf(Ot[0] * inv, Ot[1] * inv),
                  pack2bf(Ot[2] * inv, Ot[3] * inv) };
    uint2 st1 = { pack2bf(Ot[4] * inv, Ot[5] * inv),
                  pack2bf(Ot[6] * inv, Ot[7] * inv) };
    *(uint2*)(orow)     = st0;
    *(uint2*)(orow + 8) = st1;
  }
}

// ---------------- out-proj + residual + LN2 -> tn --------------------------
// 64 tok/block, 256 thr, LDS 25.6KB -> 6 blk/CU. Waves 0-1 do out-proj
// (each: 3 col-tiles x 4 m-tiles, weights in regs); waves 2-3 copy conv cols
// to LDS. x1 outproj cols written back into att slots 0..95 (attn values
// dead after the MFMA reads; the wave-0 reads of cols 48..63 that may race
// wave-1's writes hit ZERO weight rows, so the race is benign).
// LN2 writes tn bf16 to global.
__global__ __launch_bounds__(256) void outproj_ln2_kernel(
    u16* __restrict__ att, const u16* __restrict__ wo,
    const float* __restrict__ boacc, const float* __restrict__ bogyr,
    const float* __restrict__ x, const float* __restrict__ g2,
    const float* __restrict__ b2v, u16* __restrict__ tn) {
  __shared__ u16 X1[64 * XnS];
  int bm = (int)blockIdx.x * 64;
  int tid = threadIdx.x;
  int wid = tid >> 6, lane = tid & 63;
  int l15 = lane & 15, quad = lane >> 4;
  if (wid < 2) {
    bf16x8 wf[2][3];
#pragma unroll
    for (int s = 0; s < 3; s++) {
      int st = wid * 3 + s;
#pragma unroll
      for (int ks = 0; ks < 2; ks++)
        wf[ks][s] = *(const bf16x8*)(wo + (size_t)(st * 16 + l15) * 64 + ks * 32 + quad * 8);
    }
    f32x4 acc[4][3] = {};
#pragma unroll
    for (int m = 0; m < 4; m++) {
      const u16* ar = att + (size_t)(bm + m * 16 + l15) * ATTW + (wid ? 48 : 0);
#pragma unroll
      for (int ks = 0; ks < 2; ks++) {
        bf16x8 af = *(const bf16x8*)(ar + ks * 32 + quad * 8);
#pragma unroll
        for (int s = 0; s < 3; s++)
          acc[m][s] = __builtin_amdgcn_mfma_f32_16x16x32_bf16(af, wf[ks][s], acc[m][s], 0, 0, 0);
      }
    }
#pragma unroll
    for (int s = 0; s < 3; s++) {
      int col = (wid * 3 + s) * 16 + l15;          // 0..95 (att slot)
      float bias = (col < 48) ? boacc[col] : bogyr[col - 48];
      int oc = (col < 48) ? col : col + 96;        // x1 column
#pragma unroll
      for (int m = 0; m < 4; m++) {
#pragma unroll
        for (int r = 0; r < 4; r++) {
          int lrow = m * 16 + quad * 4 + r;
          float v = acc[m][s][r] + bias + x[(size_t)(bm + lrow) * EMB + oc];
          u16 bv = f2bf(v);
          X1[lrow * XnS + oc] = bv;
          att[(size_t)(bm + lrow) * ATTW + col] = bv;
        }
      }
    }
  } else {
    int trow = (wid - 2) * 32 + (lane >> 1);
    int half = lane & 1;
    const u16* src = att + (size_t)(bm + trow) * ATTW + 96 + half * 48;
    u16* dst = X1 + trow * XnS + 48 + half * 48;
#pragma unroll
    for (int j = 0; j < 48; j += 8)
      *(uint4*)(dst + j) = *(const uint4*)(src + j);
  }
  __syncthreads();
  // LN2: 4 threads/token, 48 cols each
  {
    int trow = tid >> 2, part = tid & 3;
    const u16* xl = X1 + trow * XnS + part * 48;
    float vals[48];
#pragma unroll
    for (int j = 0; j < 48; j += 8) {
      u16 raw[8];
      *(uint4*)raw = *(const uint4*)(xl + j);
#pragma unroll
      for (int u = 0; u < 8; u++) vals[j + u] = bf2f(raw[u]);
    }
    float s = 0.0f, s2 = 0.0f;
#pragma unroll
    for (int j = 0; j < 48; j++) { s += vals[j]; s2 += vals[j] * vals[j]; }
    s += __shfl_xor(s, 1); s2 += __shfl_xor(s2, 1);
    s += __shfl_xor(s, 2); s2 += __shfl_xor(s2, 2);
    float mean = s * (1.0f / EMB);
    float var  = s2 * (1.0f / EMB) - mean * mean;
    float rs   = rsqrtf(var + 1e-6f);
    const float* gp = g2 + part * 48;
    const float* bp = b2v + part * 48;
    u16 obuf[48];
#pragma unroll
    for (int j = 0; j < 48; j += 2) {
      uint32_t w = pack2bf((vals[j] - mean) * rs * gp[j] + bp[j],
                           (vals[j + 1] - mean) * rs * gp[j + 1] + bp[j + 1]);
      *(uint32_t*)(obuf + j) = w;
    }
    u16* tr = tn + (size_t)(bm + trow) * TNW + part * 48;
#pragma unroll
    for (int j = 0; j < 48; j += 8)
      *(uint4*)(tr + j) = *(const uint4*)(obuf + j);
  }
}

// ---------------- FFN gemm1: w1 LDS-stationary, zero main-loop barriers ----
// 1 block/CU (grid 256), 512 thr. Whole w1 (384x192) staged once in LDS
// (stride 200 u16: 2-way bank alias only). Each wave owns 48 h1 cols and
// streams 256 tokens from global in 4-m-tile chunks (12 indep MFMAs/kk).
// NOTE staging: uint4 = 8 u16 -> chunk stride is sg*8 (round-5 bug was sg*16).
__global__ __launch_bounds__(512) void ffn1_kernel(const u16* __restrict__ tn,
    const u16* __restrict__ w1b, const float* __restrict__ b1,
    u16* __restrict__ h1) {
  __shared__ u16 W1[384 * W1S];  // 153,600 B
  int tid = threadIdx.x;
  for (int i = tid; i < 384 * 24; i += 512) {
    int r = i / 24, sg = i % 24;
    *(uint4*)(W1 + r * W1S + sg * 8) = *(const uint4*)(w1b + r * 192 + sg * 8);
  }
  __syncthreads();
  int wid = tid >> 6, lane = tid & 63;
  int l15 = lane & 15, quad = lane >> 4;
  int tok0 = (int)blockIdx.x * 256;
  float bias[3];
#pragma unroll
  for (int s = 0; s < 3; s++) bias[s] = b1[(wid * 3 + s) * 16 + l15];
#pragma unroll 1
  for (int mc = 0; mc < 4; mc++) {
    int tb = tok0 + mc * 64;
    f32x4 acc[4][3] = {};
#pragma unroll
    for (int kk = 0; kk < 192; kk += 32) {
      bf16x8 af[4];
#pragma unroll
      for (int m = 0; m < 4; m++)
        af[m] = *(const bf16x8*)(tn + (size_t)(tb + m * 16 + l15) * TNW + kk + quad * 8);
#pragma unroll
      for (int s = 0; s < 3; s++) {
        bf16x8 bf = *(const bf16x8*)(W1 + (size_t)((wid * 3 + s) * 16 + l15) * W1S + kk + quad * 8);
#pragma unroll
        for (int m = 0; m < 4; m++)
          acc[m][s] = __builtin_amdgcn_mfma_f32_16x16x32_bf16(af[m], bf, acc[m][s], 0, 0, 0);
      }
    }
#pragma unroll
    for (int m = 0; m < 4; m++) {
#pragma unroll
      for (int s = 0; s < 3; s++) {
        int col = (wid * 3 + s) * 16 + l15;
#pragma unroll
        for (int r = 0; r < 4; r++) {
          float v = acc[m][s][r] + bias[s];
          v = v > 0.0f ? v : 0.0f;
          h1[(size_t)(tb + m * 16 + quad * 4 + r) * H1W + col] = f2bf(v);
        }
      }
    }
  }
}

// ---------------- FFN gemm2 + residual: w2 LDS-stationary ------------------
// 1 block/CU (grid 256), 384 thr (6 waves x 2 col-tiles = 12 tiles of N=192).
// Reads h1 + x1 (att buffer, remapped cols), writes fp32 out.
__global__ __launch_bounds__(384) void ffn2_kernel(const u16* __restrict__ h1,
    const u16* __restrict__ w2b, const float* __restrict__ b2,
    const u16* __restrict__ att, float* __restrict__ out) {
  __shared__ u16 W2[192 * W2S];  // 150,528 B
  int tid = threadIdx.x;
  for (int i = tid; i < 192 * 48; i += 384) {
    int r = i / 48, sg = i % 48;
    *(uint4*)(W2 + r * W2S + sg * 8) = *(const uint4*)(w2b + r * 384 + sg * 8);
  }
  __syncthreads();
  int wid = tid >> 6, lane = tid & 63;
  int l15 = lane & 15, quad = lane >> 4;
  int tok0 = (int)blockIdx.x * 256;
  float bias[2];
  int aoff[2];
#pragma unroll
  for (int s = 0; s < 2; s++) {
    int col = (wid * 2 + s) * 16 + l15;
    bias[s] = b2[col];
    aoff[s] = (col < 48) ? col : ((col < 144) ? col + 48 : col - 96);
  }
#pragma unroll 1
  for (int mc = 0; mc < 4; mc++) {
    int tb = tok0 + mc * 64;
    f32x4 acc[4][2] = {};
#pragma unroll
    for (int kk = 0; kk < 384; kk += 32) {
      bf16x8 af[4];
#pragma unroll
      for (int m = 0; m < 4; m++)
        af[m] = *(const bf16x8*)(h1 + (size_t)(tb + m * 16 + l15) * H1W + kk + quad * 8);
#pragma unroll
      for (int s = 0; s < 2; s++) {
        bf16x8 bf = *(const bf16x8*)(W2 + (size_t)((wid * 2 + s) * 16 + l15) * W2S + kk + quad * 8);
#pragma unroll
        for (int m = 0; m < 4; m++)
          acc[m][s] = __builtin_amdgcn_mfma_f32_16x16x32_bf16(af[m], bf, acc[m][s], 0, 0, 0);
      }
    }
#pragma unroll
    for (int m = 0; m < 4; m++) {
#pragma unroll
      for (int s = 0; s < 2; s++) {
        int col = (wid * 2 + s) * 16 + l15;
#pragma unroll
        for (int r = 0; r < 4; r++) {
          int tok = tb + m * 16 + quad * 4 + r;
          float v = acc[m][s][r] + bias[s];
          v = v > 0.0f ? v : 0.0f;
          out[(size_t)tok * EMB + col] = v + bf2f(att[(size_t)tok * ATTW + aoff[s]]);
        }
      }
    }
  }
}

extern "C" void kernel_launch(void* const* d_in, const int* in_sizes, int n_in,
                              void* d_out, int out_size, void* d_ws, size_t ws_size,
                              hipStream_t stream) {
  const float* x         = (const float*)d_in[0];
  const float* ln1_g     = (const float*)d_in[1];
  const float* ln1_b     = (const float*)d_in[2];
  const float* acc_wqkv  = (const float*)d_in[3];
  const float* acc_bqkv  = (const float*)d_in[4];
  const float* acc_wo    = (const float*)d_in[5];
  const float* acc_bo    = (const float*)d_in[6];
  const float* gyro_wqkv = (const float*)d_in[7];
  const float* gyro_bqkv = (const float*)d_in[8];
  const float* gyro_wo   = (const float*)d_in[9];
  const float* gyro_bo   = (const float*)d_in[10];
  const float* conv_w    = (const float*)d_in[11];
  const float* ln2_g     = (const float*)d_in[12];
  const float* ln2_b     = (const float*)d_in[13];
  const float* w1        = (const float*)d_in[14];
  const float* b1        = (const float*)d_in[15];
  const float* w2        = (const float*)d_in[16];
  const float* b2        = (const float*)d_in[17];
  float* out = (float*)d_out;
  char* ws = (char*)d_ws;

  u16* qkvb = (u16*)(ws);                      // [N,288] bf16  37,748,736
  u16* tnb  = (u16*)(ws);                      // [N,192] bf16  25,165,824 (aliases dead qkvb)
  u16* attb = (u16*)(ws + 37748736);           // [N,192] bf16  25,165,824
  u16* w1b  = (u16*)(ws + 62914560);           // 147,456
  u16* w2b  = (u16*)(ws + 63062016);           // 147,456
  u16* wqp  = (u16*)(ws + 63209472);           // 36,864
  u16* wop  = (u16*)(ws + 63246336);           // 12,288
  u16* h1b  = (u16*)(ws + 63258624);           // [N,384] bf16  50,331,648 -> end 113,590,272

  pack_kernel<<<672, 256, 0, stream>>>(w1, w2, acc_wqkv, gyro_wqkv, acc_wo,
                                       gyro_wo, w1b, w2b, wqp, wop);
  ln1_qkv_conv_kernel<<<NTOK / 64, 256, 0, stream>>>(
      x, ln1_g, ln1_b, wqp, acc_bqkv, gyro_bqkv, conv_w, qkvb, attb);
  attn_kernel<<<NB * 6, 256, 0, stream>>>(qkvb, attb);
  outproj_ln2_kernel<<<NTOK / 64, 256, 0, stream>>>(
      attb, wop, acc_bo, gyro_bo, x, ln2_g, ln2_b, tnb);
  ffn1_kernel<<<256, 512, 0, stream>>>(tnb, w1b, b1, h1b);
  ffn2_kernel<<<256, 384, 0, stream>>>(h1b, w2b, b2, attb, out);
}

// Round 7
// 320.125 us; speedup vs baseline: 1.1547x; 1.0524x over previous
//
#include <hip/hip_runtime.h>
#include <stdint.h>

typedef unsigned short u16;
typedef short bf16x8 __attribute__((ext_vector_type(8)));
typedef float f32x4 __attribute__((ext_vector_type(4)));
typedef float f32x16 __attribute__((ext_vector_type(16)));
typedef uint32_t u32x4 __attribute__((ext_vector_type(4)));

#define NB   128
#define SEQ  512
#define EMB  192
#define NTOK (NB * SEQ)   // 65536
#define F1DIM 384
#define ATTW 192          // att row (u16): x1 cols 0..47 & 144..191 at slots 0..95 after outproj; conv(x1[48:144]) at 96..191
#define VTP  520          // V^T row stride (u16)
#define KTS  24           // K row stride (u16)
#define XnS  200          // xn/x1 LDS row stride (u16): 400B, 16B-aligned
#define TNW  192          // tn global row (u16)
#define H1W  384          // h1 global row (u16)
#define W1S  200          // w1 LDS row stride (u16): 400B, 2-way bank alias only
#define W2S  392          // w2 LDS row stride (u16): 784B, 2-way bank alias only

__device__ __forceinline__ float bf2f(u16 u) {
  union { uint32_t u; float f; } v; v.u = ((uint32_t)u) << 16; return v.f;
}
__device__ __forceinline__ u16 f2bf(float f) {
  union { float f; uint32_t u; } v; v.f = f;
  uint32_t r = v.u + 0x7fffu + ((v.u >> 16) & 1u);
  return (u16)(r >> 16);
}
__device__ __forceinline__ uint32_t pack2bf(float a, float b) {
  return (uint32_t)f2bf(a) | ((uint32_t)f2bf(b) << 16);
}

// ---------------- pack all weights (one launch) ----------------------------
__global__ __launch_bounds__(256) void pack_kernel(const float* __restrict__ w1,
    const float* __restrict__ w2, const float* __restrict__ wqa,
    const float* __restrict__ wqg, const float* __restrict__ woa,
    const float* __restrict__ wog, u16* __restrict__ w1b, u16* __restrict__ w2b,
    u16* __restrict__ wqp, u16* __restrict__ wop) {
  int idx = (int)blockIdx.x * 256 + (int)threadIdx.x;
  if (idx < 73728) {
    w1b[idx] = f2bf(w1[idx]);
  } else if (idx < 147456) {
    w2b[idx - 73728] = f2bf(w2[idx - 73728]);
  } else if (idx < 165888) {
    int i = idx - 147456;
    int row = i >> 6, k = i & 63;
    float v = 0.0f;
    if (k < 48) v = (row < 144) ? wqa[row * 48 + k] : wqg[(row - 144) * 48 + k];
    wqp[i] = f2bf(v);
  } else if (idx < 172032) {
    int i = idx - 165888;
    int row = i >> 6, k = i & 63;
    float v = 0.0f;
    if (k < 48) v = (row < 48) ? woa[row * 48 + k] : wog[(row - 48) * 48 + k];
    wop[i] = f2bf(v);
  }
}

// ---------------- fused LN1 + QKV-proj (MFMA) + conv -----------------------
__global__ __launch_bounds__(256) void ln1_qkv_conv_kernel(
    const float* __restrict__ x, const float* __restrict__ g,
    const float* __restrict__ b, const u16* __restrict__ wq,
    const float* __restrict__ bacc, const float* __restrict__ bgyr,
    const float* __restrict__ cw, u16* __restrict__ qkv,
    u16* __restrict__ att) {
  __shared__ u16 Xn[64 * XnS];
  int bm = (int)blockIdx.x * 64;
  int tid = threadIdx.x;
  int trow = tid >> 2, part = tid & 3;
  int tok = bm + trow;
  const float* xr = x + (size_t)tok * EMB + part * 48;
  float vals[48];
#pragma unroll
  for (int j = 0; j < 48; j += 4) {
    float4 v = *(const float4*)(xr + j);
    vals[j] = v.x; vals[j + 1] = v.y; vals[j + 2] = v.z; vals[j + 3] = v.w;
  }
  float s = 0.0f, s2 = 0.0f;
#pragma unroll
  for (int j = 0; j < 48; j++) { s += vals[j]; s2 += vals[j] * vals[j]; }
  s += __shfl_xor(s, 1); s2 += __shfl_xor(s2, 1);
  s += __shfl_xor(s, 2); s2 += __shfl_xor(s2, 2);
  float mean = s * (1.0f / EMB);
  float var  = s2 * (1.0f / EMB) - mean * mean;
  float rs   = rsqrtf(var + 1e-6f);
  {
    u16* xnrow = Xn + trow * XnS + part * 48;
    const float* gp = g + part * 48;
    const float* bp = b + part * 48;
#pragma unroll
    for (int j = 0; j < 48; j += 2) {
      uint32_t w = pack2bf((vals[j] - mean) * rs * gp[j] + bp[j],
                           (vals[j + 1] - mean) * rs * gp[j + 1] + bp[j + 1]);
      *(uint32_t*)(xnrow + j) = w;
    }
  }
  __syncthreads();
  int wid = tid >> 6, lane = tid & 63;
  int l15 = lane & 15, quad = lane >> 4;
  const u16* arow_l = Xn + (wid * 16 + l15) * XnS;
  f32x4 acc[18] = {};
#pragma unroll
  for (int ks = 0; ks < 2; ks++) {
    int kk = ks * 32;
    bf16x8 af_a = *(const bf16x8*)(arow_l + kk + quad * 8);
    bf16x8 af_g = *(const bf16x8*)(arow_l + 96 + kk + quad * 8);
#pragma unroll
    for (int st = 0; st < 18; st++) {
      bf16x8 bf = *(const bf16x8*)(wq + (size_t)(st * 16 + l15) * 64 + kk + quad * 8);
      acc[st] = __builtin_amdgcn_mfma_f32_16x16x32_bf16(st < 9 ? af_a : af_g,
                                                        bf, acc[st], 0, 0, 0);
    }
  }
#pragma unroll
  for (int st = 0; st < 18; st++) {
    int col = st * 16 + l15;
    int cc = (col < 144) ? col : col - 144;
    float bias = (col < 144) ? bacc[cc] : bgyr[cc];
    float qs = (cc < 48) ? 0.36067376022f : 1.0f;  // 0.25*log2(e): exp2-domain scores
#pragma unroll
    for (int r = 0; r < 4; r++) {
      int orow = bm + wid * 16 + quad * 4 + r;
      qkv[(size_t)orow * 288 + col] = f2bf((acc[st][r] + bias) * qs);
    }
  }
  {
    int wr = trow & 3;
    float w15[15];
#pragma unroll
    for (int k = 0; k < 15; k++) w15[k] = cw[wr * 15 + k];
    float win[38];
    int base = part * 24 - 7;
#pragma unroll
    for (int i = 0; i < 38; i++) {
      int p = base + i;
      win[i] = (p >= 0 && p < 96) ? bf2f(Xn[trow * XnS + 48 + p]) : 0.0f;
    }
    const float* xres = x + (size_t)tok * EMB + 48 + part * 24;
    u16* orow = att + (size_t)tok * ATTW + 96 + part * 24;
#pragma unroll
    for (int c = 0; c < 24; c += 4) {
      float4 r4 = *(const float4*)(xres + c);
      float o[4];
#pragma unroll
      for (int u = 0; u < 4; u++) {
        float sc = 0.0f;
#pragma unroll
        for (int k = 0; k < 15; k++) sc += win[c + u + k] * w15[k];
        o[u] = sc;
      }
      *(uint32_t*)(orow + c)     = pack2bf(o[0] + r4.x, o[1] + r4.y);
      *(uint32_t*)(orow + c + 2) = pack2bf(o[2] + r4.z, o[3] + r4.w);
    }
  }
}

// ---------------- MFMA flash attention, max-free exp2 softmax --------------
// 512 thr / 8 waves (2 q-tiles each): 24 waves/CU vs 12 — attn was
// latency-bound (VALU 69%, Mfma 9.7%, occ 25.7% yet static VALU count ~6x
// below measured busy). permlane32_swap (1 VALU op) replaces each
// {2x ds_bpermute + 4x cndmask} group: removes the ~120cy LDS round-trip
// from every kt-iteration's critical path.
__global__ __launch_bounds__(512) void attn_kernel(const u16* __restrict__ qkv,
                                                   u16* __restrict__ att) {
  __shared__ u16 Kt[SEQ * KTS];
  __shared__ u16 Vt[17 * VTP];
  int bid = blockIdx.x;
  int hh  = bid % 3;
  int brb = (bid / 3) & 1;
  int b   = bid / 6;
  int tid = threadIdx.x;
  size_t tokbase = (size_t)b * SEQ;
  int qoff = brb * 144 + hh * 16;
  int koff = qoff + 48;
  int voff = qoff + 96;
  {
    int r = tid;  // 512 threads cover SEQ exactly
    const u16* src = qkv + (tokbase + r) * 288;
    *(uint4*)(Kt + r * KTS)     = *(const uint4*)(src + koff);
    *(uint4*)(Kt + r * KTS + 8) = *(const uint4*)(src + koff + 8);
    u16 tmp[16];
    *(uint4*)(tmp)     = *(const uint4*)(src + voff);
    *(uint4*)(tmp + 8) = *(const uint4*)(src + voff + 8);
#pragma unroll
    for (int j = 0; j < 16; j++) Vt[j * VTP + r] = tmp[j];
    Vt[16 * VTP + r] = 0x3F80;  // ones row -> l from the PV MFMA
  }
  __syncthreads();
  int wave = tid >> 6, lane = tid & 63;
  int q31 = lane & 31, h = lane >> 5;
  int dcl = (q31 < 16) ? q31 : 16;
#pragma unroll 1
  for (int qi = 0; qi < 2; qi++) {
    int qrow = (wave * 2 + qi) * 32 + q31;
    bf16x8 qfrag = *(const bf16x8*)(qkv + (tokbase + qrow) * 288 + qoff + h * 8);
    f32x16 Ot = {};
#pragma unroll 2
    for (int kt = 0; kt < 16; kt++) {
      bf16x8 kfrag = *(const bf16x8*)(Kt + (kt * 32 + q31) * KTS + h * 8);
      f32x16 zc = {};
      f32x16 S = __builtin_amdgcn_mfma_f32_32x32x16_bf16(kfrag, qfrag, zc, 0, 0, 0);
      uint32_t pk[8];
#pragma unroll
      for (int i = 0; i < 8; i++) {
        union { float f; uint32_t u; } a0, a1;
        a0.f = exp2f(S[2 * i]);
        a1.f = exp2f(S[2 * i + 1]);
        pk[i] = __builtin_amdgcn_perm(a1.u, a0.u, 0x07060302u);
      }
      // permlane32_swap(a,b): a' = {a.lo | b.lo}, b' = {a.hi | b.hi}
      // a' == (h ? b_from_low : a_own), b' == (h ? b_own : a_from_high)
      uint32_t s0a = pk[0], s0b = pk[2];
      uint32_t s1a = pk[1], s1b = pk[3];
      uint32_t s2a = pk[4], s2b = pk[6];
      uint32_t s3a = pk[5], s3b = pk[7];
      asm("v_permlane32_swap_b32 %0, %1" : "+v"(s0a), "+v"(s0b));
      asm("v_permlane32_swap_b32 %0, %1" : "+v"(s1a), "+v"(s1b));
      asm("v_permlane32_swap_b32 %0, %1" : "+v"(s2a), "+v"(s2b));
      asm("v_permlane32_swap_b32 %0, %1" : "+v"(s3a), "+v"(s3b));
      u32x4 t1 = { s0a, s1a, s0b, s1b };
      u32x4 t2 = { s2a, s3a, s2b, s3b };
      bf16x8 pb1 = __builtin_bit_cast(bf16x8, t1);
      bf16x8 pb2 = __builtin_bit_cast(bf16x8, t2);
      bf16x8 av1 = *(const bf16x8*)(Vt + dcl * VTP + kt * 32 + h * 8);
      bf16x8 av2 = *(const bf16x8*)(Vt + dcl * VTP + kt * 32 + 16 + h * 8);
      Ot = __builtin_amdgcn_mfma_f32_32x32x16_bf16(av1, pb1, Ot, 0, 0, 0);
      Ot = __builtin_amdgcn_mfma_f32_32x32x16_bf16(av2, pb2, Ot, 0, 0, 0);
    }
    float inv = 1.0f / Ot[8];
    u16* orow = att + (tokbase + qrow) * ATTW + brb * 48 + hh * 16 + 4 * h;
    uint2 st0 = { pack2bf(Ot[0] * inv, Ot[1] * inv),
                  pack2bf(Ot[2] * inv, Ot[3] * inv) };
    uint2 st1 = { pack2bf(Ot[4] * inv, Ot[5] * inv),
                  pack2bf(Ot[6] * inv, Ot[7] * inv) };
    *(uint2*)(orow)     = st0;
    *(uint2*)(orow + 8) = st1;
  }
}

// ---------------- out-proj + residual + LN2 -> tn --------------------------
// 64 tok/block, 256 thr, LDS 25.6KB -> 6 blk/CU. Waves 0-1 do out-proj
// (each: 3 col-tiles x 4 m-tiles, weights in regs); waves 2-3 copy conv cols
// to LDS. x1 outproj cols written back into att slots 0..95 (attn values
// dead after the MFMA reads; the wave-0 reads of cols 48..63 that may race
// wave-1's writes hit ZERO weight rows, so the race is benign).
// LN2 writes tn bf16 to global.
__global__ __launch_bounds__(256) void outproj_ln2_kernel(
    u16* __restrict__ att, const u16* __restrict__ wo,
    const float* __restrict__ boacc, const float* __restrict__ bogyr,
    const float* __restrict__ x, const float* __restrict__ g2,
    const float* __restrict__ b2v, u16* __restrict__ tn) {
  __shared__ u16 X1[64 * XnS];
  int bm = (int)blockIdx.x * 64;
  int tid = threadIdx.x;
  int wid = tid >> 6, lane = tid & 63;
  int l15 = lane & 15, quad = lane >> 4;
  if (wid < 2) {
    bf16x8 wf[2][3];
#pragma unroll
    for (int s = 0; s < 3; s++) {
      int st = wid * 3 + s;
#pragma unroll
      for (int ks = 0; ks < 2; ks++)
        wf[ks][s] = *(const bf16x8*)(wo + (size_t)(st * 16 + l15) * 64 + ks * 32 + quad * 8);
    }
    f32x4 acc[4][3] = {};
#pragma unroll
    for (int m = 0; m < 4; m++) {
      const u16* ar = att + (size_t)(bm + m * 16 + l15) * ATTW + (wid ? 48 : 0);
#pragma unroll
      for (int ks = 0; ks < 2; ks++) {
        bf16x8 af = *(const bf16x8*)(ar + ks * 32 + quad * 8);
#pragma unroll
        for (int s = 0; s < 3; s++)
          acc[m][s] = __builtin_amdgcn_mfma_f32_16x16x32_bf16(af, wf[ks][s], acc[m][s], 0, 0, 0);
      }
    }
#pragma unroll
    for (int s = 0; s < 3; s++) {
      int col = (wid * 3 + s) * 16 + l15;          // 0..95 (att slot)
      float bias = (col < 48) ? boacc[col] : bogyr[col - 48];
      int oc = (col < 48) ? col : col + 96;        // x1 column
#pragma unroll
      for (int m = 0; m < 4; m++) {
#pragma unroll
        for (int r = 0; r < 4; r++) {
          int lrow = m * 16 + quad * 4 + r;
          float v = acc[m][s][r] + bias + x[(size_t)(bm + lrow) * EMB + oc];
          u16 bv = f2bf(v);
          X1[lrow * XnS + oc] = bv;
          att[(size_t)(bm + lrow) * ATTW + col] = bv;
        }
      }
    }
  } else {
    int trow = (wid - 2) * 32 + (lane >> 1);
    int half = lane & 1;
    const u16* src = att + (size_t)(bm + trow) * ATTW + 96 + half * 48;
    u16* dst = X1 + trow * XnS + 48 + half * 48;
#pragma unroll
    for (int j = 0; j < 48; j += 8)
      *(uint4*)(dst + j) = *(const uint4*)(src + j);
  }
  __syncthreads();
  // LN2: 4 threads/token, 48 cols each
  {
    int trow = tid >> 2, part = tid & 3;
    const u16* xl = X1 + trow * XnS + part * 48;
    float vals[48];
#pragma unroll
    for (int j = 0; j < 48; j += 8) {
      u16 raw[8];
      *(uint4*)raw = *(const uint4*)(xl + j);
#pragma unroll
      for (int u = 0; u < 8; u++) vals[j + u] = bf2f(raw[u]);
    }
    float s = 0.0f, s2 = 0.0f;
#pragma unroll
    for (int j = 0; j < 48; j++) { s += vals[j]; s2 += vals[j] * vals[j]; }
    s += __shfl_xor(s, 1); s2 += __shfl_xor(s2, 1);
    s += __shfl_xor(s, 2); s2 += __shfl_xor(s2, 2);
    float mean = s * (1.0f / EMB);
    float var  = s2 * (1.0f / EMB) - mean * mean;
    float rs   = rsqrtf(var + 1e-6f);
    const float* gp = g2 + part * 48;
    const float* bp = b2v + part * 48;
    u16 obuf[48];
#pragma unroll
    for (int j = 0; j < 48; j += 2) {
      uint32_t w = pack2bf((vals[j] - mean) * rs * gp[j] + bp[j],
                           (vals[j + 1] - mean) * rs * gp[j + 1] + bp[j + 1]);
      *(uint32_t*)(obuf + j) = w;
    }
    u16* tr = tn + (size_t)(bm + trow) * TNW + part * 48;
#pragma unroll
    for (int j = 0; j < 48; j += 8)
      *(uint4*)(tr + j) = *(const uint4*)(obuf + j);
  }
}

// ---------------- FFN gemm1: w1 LDS-stationary, zero main-loop barriers ----
// 1 block/CU (grid 256), 512 thr. Whole w1 (384x192) staged once in LDS.
__global__ __launch_bounds__(512) void ffn1_kernel(const u16* __restrict__ tn,
    const u16* __restrict__ w1b, const float* __restrict__ b1,
    u16* __restrict__ h1) {
  __shared__ u16 W1[384 * W1S];  // 153,600 B
  int tid = threadIdx.x;
  for (int i = tid; i < 384 * 24; i += 512) {
    int r = i / 24, sg = i % 24;
    *(uint4*)(W1 + r * W1S + sg * 8) = *(const uint4*)(w1b + r * 192 + sg * 8);
  }
  __syncthreads();
  int wid = tid >> 6, lane = tid & 63;
  int l15 = lane & 15, quad = lane >> 4;
  int tok0 = (int)blockIdx.x * 256;
  float bias[3];
#pragma unroll
  for (int s = 0; s < 3; s++) bias[s] = b1[(wid * 3 + s) * 16 + l15];
#pragma unroll 1
  for (int mc = 0; mc < 4; mc++) {
    int tb = tok0 + mc * 64;
    f32x4 acc[4][3] = {};
#pragma unroll
    for (int kk = 0; kk < 192; kk += 32) {
      bf16x8 af[4];
#pragma unroll
      for (int m = 0; m < 4; m++)
        af[m] = *(const bf16x8*)(tn + (size_t)(tb + m * 16 + l15) * TNW + kk + quad * 8);
#pragma unroll
      for (int s = 0; s < 3; s++) {
        bf16x8 bf = *(const bf16x8*)(W1 + (size_t)((wid * 3 + s) * 16 + l15) * W1S + kk + quad * 8);
#pragma unroll
        for (int m = 0; m < 4; m++)
          acc[m][s] = __builtin_amdgcn_mfma_f32_16x16x32_bf16(af[m], bf, acc[m][s], 0, 0, 0);
      }
    }
#pragma unroll
    for (int m = 0; m < 4; m++) {
#pragma unroll
      for (int s = 0; s < 3; s++) {
        int col = (wid * 3 + s) * 16 + l15;
#pragma unroll
        for (int r = 0; r < 4; r++) {
          float v = acc[m][s][r] + bias[s];
          v = v > 0.0f ? v : 0.0f;
          h1[(size_t)(tb + m * 16 + quad * 4 + r) * H1W + col] = f2bf(v);
        }
      }
    }
  }
}

// ---------------- FFN gemm2 + residual: w2 LDS-stationary ------------------
// 1 block/CU (grid 256), 384 thr (6 waves x 2 col-tiles = 12 tiles of N=192).
__global__ __launch_bounds__(384) void ffn2_kernel(const u16* __restrict__ h1,
    const u16* __restrict__ w2b, const float* __restrict__ b2,
    const u16* __restrict__ att, float* __restrict__ out) {
  __shared__ u16 W2[192 * W2S];  // 150,528 B
  int tid = threadIdx.x;
  for (int i = tid; i < 192 * 48; i += 384) {
    int r = i / 48, sg = i % 48;
    *(uint4*)(W2 + r * W2S + sg * 8) = *(const uint4*)(w2b + r * 384 + sg * 8);
  }
  __syncthreads();
  int wid = tid >> 6, lane = tid & 63;
  int l15 = lane & 15, quad = lane >> 4;
  int tok0 = (int)blockIdx.x * 256;
  float bias[2];
  int aoff[2];
#pragma unroll
  for (int s = 0; s < 2; s++) {
    int col = (wid * 2 + s) * 16 + l15;
    bias[s] = b2[col];
    aoff[s] = (col < 48) ? col : ((col < 144) ? col + 48 : col - 96);
  }
#pragma unroll 1
  for (int mc = 0; mc < 4; mc++) {
    int tb = tok0 + mc * 64;
    f32x4 acc[4][2] = {};
#pragma unroll
    for (int kk = 0; kk < 384; kk += 32) {
      bf16x8 af[4];
#pragma unroll
      for (int m = 0; m < 4; m++)
        af[m] = *(const bf16x8*)(h1 + (size_t)(tb + m * 16 + l15) * H1W + kk + quad * 8);
#pragma unroll
      for (int s = 0; s < 2; s++) {
        bf16x8 bf = *(const bf16x8*)(W2 + (size_t)((wid * 2 + s) * 16 + l15) * W2S + kk + quad * 8);
#pragma unroll
        for (int m = 0; m < 4; m++)
          acc[m][s] = __builtin_amdgcn_mfma_f32_16x16x32_bf16(af[m], bf, acc[m][s], 0, 0, 0);
      }
    }
#pragma unroll
    for (int m = 0; m < 4; m++) {
#pragma unroll
      for (int s = 0; s < 2; s++) {
        int col = (wid * 2 + s) * 16 + l15;
#pragma unroll
        for (int r = 0; r < 4; r++) {
          int tok = tb + m * 16 + quad * 4 + r;
          float v = acc[m][s][r] + bias[s];
          v = v > 0.0f ? v : 0.0f;
          out[(size_t)tok * EMB + col] = v + bf2f(att[(size_t)tok * ATTW + aoff[s]]);
        }
      }
    }
  }
}

extern "C" void kernel_launch(void* const* d_in, const int* in_sizes, int n_in,
                              void* d_out, int out_size, void* d_ws, size_t ws_size,
                              hipStream_t stream) {
  const float* x         = (const float*)d_in[0];
  const float* ln1_g     = (const float*)d_in[1];
  const float* ln1_b     = (const float*)d_in[2];
  const float* acc_wqkv  = (const float*)d_in[3];
  const float* acc_bqkv  = (const float*)d_in[4];
  const float* acc_wo    = (const float*)d_in[5];
  const float* acc_bo    = (const float*)d_in[6];
  const float* gyro_wqkv = (const float*)d_in[7];
  const float* gyro_bqkv = (const float*)d_in[8];
  const float* gyro_wo   = (const float*)d_in[9];
  const float* gyro_bo   = (const float*)d_in[10];
  const float* conv_w    = (const float*)d_in[11];
  const float* ln2_g     = (const float*)d_in[12];
  const float* ln2_b     = (const float*)d_in[13];
  const float* w1        = (const float*)d_in[14];
  const float* b1        = (const float*)d_in[15];
  const float* w2        = (const float*)d_in[16];
  const float* b2        = (const float*)d_in[17];
  float* out = (float*)d_out;
  char* ws = (char*)d_ws;

  u16* qkvb = (u16*)(ws);                      // [N,288] bf16  37,748,736
  u16* tnb  = (u16*)(ws);                      // [N,192] bf16  25,165,824 (aliases dead qkvb)
  u16* attb = (u16*)(ws + 37748736);           // [N,192] bf16  25,165,824
  u16* w1b  = (u16*)(ws + 62914560);           // 147,456
  u16* w2b  = (u16*)(ws + 63062016);           // 147,456
  u16* wqp  = (u16*)(ws + 63209472);           // 36,864
  u16* wop  = (u16*)(ws + 63246336);           // 12,288
  u16* h1b  = (u16*)(ws + 63258624);           // [N,384] bf16  50,331,648 -> end 113,590,272

  pack_kernel<<<672, 256, 0, stream>>>(w1, w2, acc_wqkv, gyro_wqkv, acc_wo,
                                       gyro_wo, w1b, w2b, wqp, wop);
  ln1_qkv_conv_kernel<<<NTOK / 64, 256, 0, stream>>>(
      x, ln1_g, ln1_b, wqp, acc_bqkv, gyro_bqkv, conv_w, qkvb, attb);
  attn_kernel<<<NB * 6, 512, 0, stream>>>(qkvb, attb);
  outproj_ln2_kernel<<<NTOK / 64, 256, 0, stream>>>(
      attb, wop, acc_bo, gyro_bo, x, ln2_g, ln2_b, tnb);
  ffn1_kernel<<<256, 512, 0, stream>>>(tnb, w1b, b1, h1b);
  ffn2_kernel<<<256, 384, 0, stream>>>(h1b, w2b, b2, attb, out);
}

// Round 8
// 299.472 us; speedup vs baseline: 1.2343x; 1.0690x over previous
//
#include <hip/hip_runtime.h>
#include <stdint.h>

typedef unsigned short u16;
typedef short bf16x8 __attribute__((ext_vector_type(8)));
typedef float f32x4 __attribute__((ext_vector_type(4)));
typedef float f32x16 __attribute__((ext_vector_type(16)));
typedef uint32_t u32x4 __attribute__((ext_vector_type(4)));

#define NB   128
#define SEQ  512
#define EMB  192
#define NTOK (NB * SEQ)   // 65536
#define F1DIM 384
#define ATTW 192          // att row (u16): x1 cols 0..47 & 144..191 at slots 0..95 after outproj; conv(x1[48:144]) at 96..191
#define VTP  520          // V^T row stride (u16)
#define KTS  24           // K row stride (u16)
#define XnS  200          // xn/x1 LDS row stride (u16): 400B, 16B-aligned
#define TNW  192          // tn global row (u16)
#define H1W  384          // h1 global row (u16)
#define W1S  200          // w1 LDS row stride (u16): 400B, 2-way bank alias only
#define W2S  392          // w2 LDS row stride (u16): 784B, 2-way bank alias only

// raw v_exp_f32: scores are pre-scaled into exp2 domain and bounded, so the
// __ocml_exp2_f32 range/denormal fixup (~4-6 VALU ops per call) is dead
// weight. Guarded so compilation can never fail.
#if __has_builtin(__builtin_amdgcn_exp2f)
#define EXP2F(x) __builtin_amdgcn_exp2f(x)
#else
#define EXP2F(x) exp2f(x)
#endif

__device__ __forceinline__ float bf2f(u16 u) {
  union { uint32_t u; float f; } v; v.u = ((uint32_t)u) << 16; return v.f;
}
__device__ __forceinline__ u16 f2bf(float f) {
  union { float f; uint32_t u; } v; v.f = f;
  uint32_t r = v.u + 0x7fffu + ((v.u >> 16) & 1u);
  return (u16)(r >> 16);
}
__device__ __forceinline__ uint32_t pack2bf(float a, float b) {
  return (uint32_t)f2bf(a) | ((uint32_t)f2bf(b) << 16);
}

// ---------------- pack all weights (one launch) ----------------------------
__global__ __launch_bounds__(256) void pack_kernel(const float* __restrict__ w1,
    const float* __restrict__ w2, const float* __restrict__ wqa,
    const float* __restrict__ wqg, const float* __restrict__ woa,
    const float* __restrict__ wog, u16* __restrict__ w1b, u16* __restrict__ w2b,
    u16* __restrict__ wqp, u16* __restrict__ wop) {
  int idx = (int)blockIdx.x * 256 + (int)threadIdx.x;
  if (idx < 73728) {
    w1b[idx] = f2bf(w1[idx]);
  } else if (idx < 147456) {
    w2b[idx - 73728] = f2bf(w2[idx - 73728]);
  } else if (idx < 165888) {
    int i = idx - 147456;
    int row = i >> 6, k = i & 63;
    float v = 0.0f;
    if (k < 48) v = (row < 144) ? wqa[row * 48 + k] : wqg[(row - 144) * 48 + k];
    wqp[i] = f2bf(v);
  } else if (idx < 172032) {
    int i = idx - 165888;
    int row = i >> 6, k = i & 63;
    float v = 0.0f;
    if (k < 48) v = (row < 48) ? woa[row * 48 + k] : wog[(row - 48) * 48 + k];
    wop[i] = f2bf(v);
  }
}

// ---------------- fused LN1 + QKV-proj (MFMA) + conv -----------------------
__global__ __launch_bounds__(256) void ln1_qkv_conv_kernel(
    const float* __restrict__ x, const float* __restrict__ g,
    const float* __restrict__ b, const u16* __restrict__ wq,
    const float* __restrict__ bacc, const float* __restrict__ bgyr,
    const float* __restrict__ cw, u16* __restrict__ qkv,
    u16* __restrict__ att) {
  __shared__ u16 Xn[64 * XnS];
  int bm = (int)blockIdx.x * 64;
  int tid = threadIdx.x;
  int trow = tid >> 2, part = tid & 3;
  int tok = bm + trow;
  const float* xr = x + (size_t)tok * EMB + part * 48;
  float vals[48];
#pragma unroll
  for (int j = 0; j < 48; j += 4) {
    float4 v = *(const float4*)(xr + j);
    vals[j] = v.x; vals[j + 1] = v.y; vals[j + 2] = v.z; vals[j + 3] = v.w;
  }
  float s = 0.0f, s2 = 0.0f;
#pragma unroll
  for (int j = 0; j < 48; j++) { s += vals[j]; s2 += vals[j] * vals[j]; }
  s += __shfl_xor(s, 1); s2 += __shfl_xor(s2, 1);
  s += __shfl_xor(s, 2); s2 += __shfl_xor(s2, 2);
  float mean = s * (1.0f / EMB);
  float var  = s2 * (1.0f / EMB) - mean * mean;
  float rs   = rsqrtf(var + 1e-6f);
  {
    u16* xnrow = Xn + trow * XnS + part * 48;
    const float* gp = g + part * 48;
    const float* bp = b + part * 48;
#pragma unroll
    for (int j = 0; j < 48; j += 2) {
      uint32_t w = pack2bf((vals[j] - mean) * rs * gp[j] + bp[j],
                           (vals[j + 1] - mean) * rs * gp[j + 1] + bp[j + 1]);
      *(uint32_t*)(xnrow + j) = w;
    }
  }
  __syncthreads();
  int wid = tid >> 6, lane = tid & 63;
  int l15 = lane & 15, quad = lane >> 4;
  const u16* arow_l = Xn + (wid * 16 + l15) * XnS;
  f32x4 acc[18] = {};
#pragma unroll
  for (int ks = 0; ks < 2; ks++) {
    int kk = ks * 32;
    bf16x8 af_a = *(const bf16x8*)(arow_l + kk + quad * 8);
    bf16x8 af_g = *(const bf16x8*)(arow_l + 96 + kk + quad * 8);
#pragma unroll
    for (int st = 0; st < 18; st++) {
      bf16x8 bf = *(const bf16x8*)(wq + (size_t)(st * 16 + l15) * 64 + kk + quad * 8);
      acc[st] = __builtin_amdgcn_mfma_f32_16x16x32_bf16(st < 9 ? af_a : af_g,
                                                        bf, acc[st], 0, 0, 0);
    }
  }
#pragma unroll
  for (int st = 0; st < 18; st++) {
    int col = st * 16 + l15;
    int cc = (col < 144) ? col : col - 144;
    float bias = (col < 144) ? bacc[cc] : bgyr[cc];
    float qs = (cc < 48) ? 0.36067376022f : 1.0f;  // 0.25*log2(e): exp2-domain scores
#pragma unroll
    for (int r = 0; r < 4; r++) {
      int orow = bm + wid * 16 + quad * 4 + r;
      qkv[(size_t)orow * 288 + col] = f2bf((acc[st][r] + bias) * qs);
    }
  }
  {
    int wr = trow & 3;
    float w15[15];
#pragma unroll
    for (int k = 0; k < 15; k++) w15[k] = cw[wr * 15 + k];
    float win[38];
    int base = part * 24 - 7;
#pragma unroll
    for (int i = 0; i < 38; i++) {
      int p = base + i;
      win[i] = (p >= 0 && p < 96) ? bf2f(Xn[trow * XnS + 48 + p]) : 0.0f;
    }
    const float* xres = x + (size_t)tok * EMB + 48 + part * 24;
    u16* orow = att + (size_t)tok * ATTW + 96 + part * 24;
#pragma unroll
    for (int c = 0; c < 24; c += 4) {
      float4 r4 = *(const float4*)(xres + c);
      float o[4];
#pragma unroll
      for (int u = 0; u < 4; u++) {
        float sc = 0.0f;
#pragma unroll
        for (int k = 0; k < 15; k++) sc += win[c + u + k] * w15[k];
        o[u] = sc;
      }
      *(uint32_t*)(orow + c)     = pack2bf(o[0] + r4.x, o[1] + r4.y);
      *(uint32_t*)(orow + c + 2) = pack2bf(o[2] + r4.z, o[3] + r4.w);
    }
  }
}

// ---------------- MFMA flash attention, max-free exp2 softmax --------------
// 512 thr / 8 waves (2 q-tiles each). permlane32_swap for the cross-half
// P exchange (round 7). Round 8: raw v_exp_f32 via EXP2F — libm exp2f was
// expanding to ~5 VALU ops (range fixup), inflating VALUBusy to ~68%.
__global__ __launch_bounds__(512) void attn_kernel(const u16* __restrict__ qkv,
                                                   u16* __restrict__ att) {
  __shared__ u16 Kt[SEQ * KTS];
  __shared__ u16 Vt[17 * VTP];
  int bid = blockIdx.x;
  int hh  = bid % 3;
  int brb = (bid / 3) & 1;
  int b   = bid / 6;
  int tid = threadIdx.x;
  size_t tokbase = (size_t)b * SEQ;
  int qoff = brb * 144 + hh * 16;
  int koff = qoff + 48;
  int voff = qoff + 96;
  {
    int r = tid;  // 512 threads cover SEQ exactly
    const u16* src = qkv + (tokbase + r) * 288;
    *(uint4*)(Kt + r * KTS)     = *(const uint4*)(src + koff);
    *(uint4*)(Kt + r * KTS + 8) = *(const uint4*)(src + koff + 8);
    u16 tmp[16];
    *(uint4*)(tmp)     = *(const uint4*)(src + voff);
    *(uint4*)(tmp + 8) = *(const uint4*)(src + voff + 8);
#pragma unroll
    for (int j = 0; j < 16; j++) Vt[j * VTP + r] = tmp[j];
    Vt[16 * VTP + r] = 0x3F80;  // ones row -> l from the PV MFMA
  }
  __syncthreads();
  int wave = tid >> 6, lane = tid & 63;
  int q31 = lane & 31, h = lane >> 5;
  int dcl = (q31 < 16) ? q31 : 16;
#pragma unroll 1
  for (int qi = 0; qi < 2; qi++) {
    int qrow = (wave * 2 + qi) * 32 + q31;
    bf16x8 qfrag = *(const bf16x8*)(qkv + (tokbase + qrow) * 288 + qoff + h * 8);
    f32x16 Ot = {};
#pragma unroll 2
    for (int kt = 0; kt < 16; kt++) {
      bf16x8 kfrag = *(const bf16x8*)(Kt + (kt * 32 + q31) * KTS + h * 8);
      f32x16 zc = {};
      f32x16 S = __builtin_amdgcn_mfma_f32_32x32x16_bf16(kfrag, qfrag, zc, 0, 0, 0);
      uint32_t pk[8];
#pragma unroll
      for (int i = 0; i < 8; i++) {
        union { float f; uint32_t u; } a0, a1;
        a0.f = EXP2F(S[2 * i]);
        a1.f = EXP2F(S[2 * i + 1]);
        pk[i] = __builtin_amdgcn_perm(a1.u, a0.u, 0x07060302u);
      }
      // permlane32_swap(a,b): a' = {a.lo | b.lo}, b' = {a.hi | b.hi}
      uint32_t s0a = pk[0], s0b = pk[2];
      uint32_t s1a = pk[1], s1b = pk[3];
      uint32_t s2a = pk[4], s2b = pk[6];
      uint32_t s3a = pk[5], s3b = pk[7];
      asm("v_permlane32_swap_b32 %0, %1" : "+v"(s0a), "+v"(s0b));
      asm("v_permlane32_swap_b32 %0, %1" : "+v"(s1a), "+v"(s1b));
      asm("v_permlane32_swap_b32 %0, %1" : "+v"(s2a), "+v"(s2b));
      asm("v_permlane32_swap_b32 %0, %1" : "+v"(s3a), "+v"(s3b));
      u32x4 t1 = { s0a, s1a, s0b, s1b };
      u32x4 t2 = { s2a, s3a, s2b, s3b };
      bf16x8 pb1 = __builtin_bit_cast(bf16x8, t1);
      bf16x8 pb2 = __builtin_bit_cast(bf16x8, t2);
      bf16x8 av1 = *(const bf16x8*)(Vt + dcl * VTP + kt * 32 + h * 8);
      bf16x8 av2 = *(const bf16x8*)(Vt + dcl * VTP + kt * 32 + 16 + h * 8);
      Ot = __builtin_amdgcn_mfma_f32_32x32x16_bf16(av1, pb1, Ot, 0, 0, 0);
      Ot = __builtin_amdgcn_mfma_f32_32x32x16_bf16(av2, pb2, Ot, 0, 0, 0);
    }
    float inv = 1.0f / Ot[8];
    u16* orow = att + (tokbase + qrow) * ATTW + brb * 48 + hh * 16 + 4 * h;
    uint2 st0 = { pack2bf(Ot[0] * inv, Ot[1] * inv),
                  pack2bf(Ot[2] * inv, Ot[3] * inv) };
    uint2 st1 = { pack2bf(Ot[4] * inv, Ot[5] * inv),
                  pack2bf(Ot[6] * inv, Ot[7] * inv) };
    *(uint2*)(orow)     = st0;
    *(uint2*)(orow + 8) = st1;
  }
}

// ---------------- out-proj + residual + LN2 -> tn --------------------------
__global__ __launch_bounds__(256) void outproj_ln2_kernel(
    u16* __restrict__ att, const u16* __restrict__ wo,
    const float* __restrict__ boacc, const float* __restrict__ bogyr,
    const float* __restrict__ x, const float* __restrict__ g2,
    const float* __restrict__ b2v, u16* __restrict__ tn) {
  __shared__ u16 X1[64 * XnS];
  int bm = (int)blockIdx.x * 64;
  int tid = threadIdx.x;
  int wid = tid >> 6, lane = tid & 63;
  int l15 = lane & 15, quad = lane >> 4;
  if (wid < 2) {
    bf16x8 wf[2][3];
#pragma unroll
    for (int s = 0; s < 3; s++) {
      int st = wid * 3 + s;
#pragma unroll
      for (int ks = 0; ks < 2; ks++)
        wf[ks][s] = *(const bf16x8*)(wo + (size_t)(st * 16 + l15) * 64 + ks * 32 + quad * 8);
    }
    f32x4 acc[4][3] = {};
#pragma unroll
    for (int m = 0; m < 4; m++) {
      const u16* ar = att + (size_t)(bm + m * 16 + l15) * ATTW + (wid ? 48 : 0);
#pragma unroll
      for (int ks = 0; ks < 2; ks++) {
        bf16x8 af = *(const bf16x8*)(ar + ks * 32 + quad * 8);
#pragma unroll
        for (int s = 0; s < 3; s++)
          acc[m][s] = __builtin_amdgcn_mfma_f32_16x16x32_bf16(af, wf[ks][s], acc[m][s], 0, 0, 0);
      }
    }
#pragma unroll
    for (int s = 0; s < 3; s++) {
      int col = (wid * 3 + s) * 16 + l15;          // 0..95 (att slot)
      float bias = (col < 48) ? boacc[col] : bogyr[col - 48];
      int oc = (col < 48) ? col : col + 96;        // x1 column
#pragma unroll
      for (int m = 0; m < 4; m++) {
#pragma unroll
        for (int r = 0; r < 4; r++) {
          int lrow = m * 16 + quad * 4 + r;
          float v = acc[m][s][r] + bias + x[(size_t)(bm + lrow) * EMB + oc];
          u16 bv = f2bf(v);
          X1[lrow * XnS + oc] = bv;
          att[(size_t)(bm + lrow) * ATTW + col] = bv;
        }
      }
    }
  } else {
    int trow = (wid - 2) * 32 + (lane >> 1);
    int half = lane & 1;
    const u16* src = att + (size_t)(bm + trow) * ATTW + 96 + half * 48;
    u16* dst = X1 + trow * XnS + 48 + half * 48;
#pragma unroll
    for (int j = 0; j < 48; j += 8)
      *(uint4*)(dst + j) = *(const uint4*)(src + j);
  }
  __syncthreads();
  // LN2: 4 threads/token, 48 cols each
  {
    int trow = tid >> 2, part = tid & 3;
    const u16* xl = X1 + trow * XnS + part * 48;
    float vals[48];
#pragma unroll
    for (int j = 0; j < 48; j += 8) {
      u16 raw[8];
      *(uint4*)raw = *(const uint4*)(xl + j);
#pragma unroll
      for (int u = 0; u < 8; u++) vals[j + u] = bf2f(raw[u]);
    }
    float s = 0.0f, s2 = 0.0f;
#pragma unroll
    for (int j = 0; j < 48; j++) { s += vals[j]; s2 += vals[j] * vals[j]; }
    s += __shfl_xor(s, 1); s2 += __shfl_xor(s2, 1);
    s += __shfl_xor(s, 2); s2 += __shfl_xor(s2, 2);
    float mean = s * (1.0f / EMB);
    float var  = s2 * (1.0f / EMB) - mean * mean;
    float rs   = rsqrtf(var + 1e-6f);
    const float* gp = g2 + part * 48;
    const float* bp = b2v + part * 48;
    u16 obuf[48];
#pragma unroll
    for (int j = 0; j < 48; j += 2) {
      uint32_t w = pack2bf((vals[j] - mean) * rs * gp[j] + bp[j],
                           (vals[j + 1] - mean) * rs * gp[j + 1] + bp[j + 1]);
      *(uint32_t*)(obuf + j) = w;
    }
    u16* tr = tn + (size_t)(bm + trow) * TNW + part * 48;
#pragma unroll
    for (int j = 0; j < 48; j += 8)
      *(uint4*)(tr + j) = *(const uint4*)(obuf + j);
  }
}

// ---------------- FFN gemm1: w1 LDS-stationary, zero main-loop barriers ----
__global__ __launch_bounds__(512) void ffn1_kernel(const u16* __restrict__ tn,
    const u16* __restrict__ w1b, const float* __restrict__ b1,
    u16* __restrict__ h1) {
  __shared__ u16 W1[384 * W1S];  // 153,600 B
  int tid = threadIdx.x;
  for (int i = tid; i < 384 * 24; i += 512) {
    int r = i / 24, sg = i % 24;
    *(uint4*)(W1 + r * W1S + sg * 8) = *(const uint4*)(w1b + r * 192 + sg * 8);
  }
  __syncthreads();
  int wid = tid >> 6, lane = tid & 63;
  int l15 = lane & 15, quad = lane >> 4;
  int tok0 = (int)blockIdx.x * 256;
  float bias[3];
#pragma unroll
  for (int s = 0; s < 3; s++) bias[s] = b1[(wid * 3 + s) * 16 + l15];
#pragma unroll 1
  for (int mc = 0; mc < 4; mc++) {
    int tb = tok0 + mc * 64;
    f32x4 acc[4][3] = {};
#pragma unroll
    for (int kk = 0; kk < 192; kk += 32) {
      bf16x8 af[4];
#pragma unroll
      for (int m = 0; m < 4; m++)
        af[m] = *(const bf16x8*)(tn + (size_t)(tb + m * 16 + l15) * TNW + kk + quad * 8);
#pragma unroll
      for (int s = 0; s < 3; s++) {
        bf16x8 bf = *(const bf16x8*)(W1 + (size_t)((wid * 3 + s) * 16 + l15) * W1S + kk + quad * 8);
#pragma unroll
        for (int m = 0; m < 4; m++)
          acc[m][s] = __builtin_amdgcn_mfma_f32_16x16x32_bf16(af[m], bf, acc[m][s], 0, 0, 0);
      }
    }
#pragma unroll
    for (int m = 0; m < 4; m++) {
#pragma unroll
      for (int s = 0; s < 3; s++) {
        int col = (wid * 3 + s) * 16 + l15;
#pragma unroll
        for (int r = 0; r < 4; r++) {
          float v = acc[m][s][r] + bias[s];
          v = v > 0.0f ? v : 0.0f;
          h1[(size_t)(tb + m * 16 + quad * 4 + r) * H1W + col] = f2bf(v);
        }
      }
    }
  }
}

// ---------------- FFN gemm2 + residual: w2 LDS-stationary ------------------
__global__ __launch_bounds__(384) void ffn2_kernel(const u16* __restrict__ h1,
    const u16* __restrict__ w2b, const float* __restrict__ b2,
    const u16* __restrict__ att, float* __restrict__ out) {
  __shared__ u16 W2[192 * W2S];  // 150,528 B
  int tid = threadIdx.x;
  for (int i = tid; i < 192 * 48; i += 384) {
    int r = i / 48, sg = i % 48;
    *(uint4*)(W2 + r * W2S + sg * 8) = *(const uint4*)(w2b + r * 384 + sg * 8);
  }
  __syncthreads();
  int wid = tid >> 6, lane = tid & 63;
  int l15 = lane & 15, quad = lane >> 4;
  int tok0 = (int)blockIdx.x * 256;
  float bias[2];
  int aoff[2];
#pragma unroll
  for (int s = 0; s < 2; s++) {
    int col = (wid * 2 + s) * 16 + l15;
    bias[s] = b2[col];
    aoff[s] = (col < 48) ? col : ((col < 144) ? col + 48 : col - 96);
  }
#pragma unroll 1
  for (int mc = 0; mc < 4; mc++) {
    int tb = tok0 + mc * 64;
    f32x4 acc[4][2] = {};
#pragma unroll
    for (int kk = 0; kk < 384; kk += 32) {
      bf16x8 af[4];
#pragma unroll
      for (int m = 0; m < 4; m++)
        af[m] = *(const bf16x8*)(h1 + (size_t)(tb + m * 16 + l15) * H1W + kk + quad * 8);
#pragma unroll
      for (int s = 0; s < 2; s++) {
        bf16x8 bf = *(const bf16x8*)(W2 + (size_t)((wid * 2 + s) * 16 + l15) * W2S + kk + quad * 8);
#pragma unroll
        for (int m = 0; m < 4; m++)
          acc[m][s] = __builtin_amdgcn_mfma_f32_16x16x32_bf16(af[m], bf, acc[m][s], 0, 0, 0);
      }
    }
#pragma unroll
    for (int m = 0; m < 4; m++) {
#pragma unroll
      for (int s = 0; s < 2; s++) {
        int col = (wid * 2 + s) * 16 + l15;
#pragma unroll
        for (int r = 0; r < 4; r++) {
          int tok = tb + m * 16 + quad * 4 + r;
          float v = acc[m][s][r] + bias[s];
          v = v > 0.0f ? v : 0.0f;
          out[(size_t)tok * EMB + col] = v + bf2f(att[(size_t)tok * ATTW + aoff[s]]);
        }
      }
    }
  }
}

extern "C" void kernel_launch(void* const* d_in, const int* in_sizes, int n_in,
                              void* d_out, int out_size, void* d_ws, size_t ws_size,
                              hipStream_t stream) {
  const float* x         = (const float*)d_in[0];
  const float* ln1_g     = (const float*)d_in[1];
  const float* ln1_b     = (const float*)d_in[2];
  const float* acc_wqkv  = (const float*)d_in[3];
  const float* acc_bqkv  = (const float*)d_in[4];
  const float* acc_wo    = (const float*)d_in[5];
  const float* acc_bo    = (const float*)d_in[6];
  const float* gyro_wqkv = (const float*)d_in[7];
  const float* gyro_bqkv = (const float*)d_in[8];
  const float* gyro_wo   = (const float*)d_in[9];
  const float* gyro_bo   = (const float*)d_in[10];
  const float* conv_w    = (const float*)d_in[11];
  const float* ln2_g     = (const float*)d_in[12];
  const float* ln2_b     = (const float*)d_in[13];
  const float* w1        = (const float*)d_in[14];
  const float* b1        = (const float*)d_in[15];
  const float* w2        = (const float*)d_in[16];
  const float* b2        = (const float*)d_in[17];
  float* out = (float*)d_out;
  char* ws = (char*)d_ws;

  u16* qkvb = (u16*)(ws);                      // [N,288] bf16  37,748,736
  u16* tnb  = (u16*)(ws);                      // [N,192] bf16  25,165,824 (aliases dead qkvb)
  u16* attb = (u16*)(ws + 37748736);           // [N,192] bf16  25,165,824
  u16* w1b  = (u16*)(ws + 62914560);           // 147,456
  u16* w2b  = (u16*)(ws + 63062016);           // 147,456
  u16* wqp  = (u16*)(ws + 63209472);           // 36,864
  u16* wop  = (u16*)(ws + 63246336);           // 12,288
  u16* h1b  = (u16*)(ws + 63258624);           // [N,384] bf16  50,331,648 -> end 113,590,272

  pack_kernel<<<672, 256, 0, stream>>>(w1, w2, acc_wqkv, gyro_wqkv, acc_wo,
                                       gyro_wo, w1b, w2b, wqp, wop);
  ln1_qkv_conv_kernel<<<NTOK / 64, 256, 0, stream>>>(
      x, ln1_g, ln1_b, wqp, acc_bqkv, gyro_bqkv, conv_w, qkvb, attb);
  attn_kernel<<<NB * 6, 512, 0, stream>>>(qkvb, attb);
  outproj_ln2_kernel<<<NTOK / 64, 256, 0, stream>>>(
      attb, wop, acc_bo, gyro_bo, x, ln2_g, ln2_b, tnb);
  ffn1_kernel<<<256, 512, 0, stream>>>(tnb, w1b, b1, h1b);
  ffn2_kernel<<<256, 384, 0, stream>>>(h1b, w2b, b2, attb, out);
}